// Round 1
// baseline (380.409 us; speedup 1.0000x reference)
//
#include <hip/hip_runtime.h>
#include <hip/hip_bf16.h>
#include <stdint.h>

#define N_PTS 131072
#define NC 256
#define NSEG 16
#define BN_EPSF 1e-5f

typedef __attribute__((ext_vector_type(8))) short bf16x8;
typedef __attribute__((ext_vector_type(4))) float f32x4;

__device__ __forceinline__ unsigned short f2bf(float f) {
  union { float f; uint32_t u; } v; v.f = f;
  uint32_t u = v.u;
  uint32_t r = (u + 0x7fffu + ((u >> 16) & 1u)) >> 16;
  return (unsigned short)r;
}
__device__ __forceinline__ float bf2f(unsigned short h) {
  union { uint32_t u; float f; } v; v.u = ((uint32_t)h) << 16; return v.f;
}

// ---------------- zero scratch stats ----------------
__global__ void k_zero(float* __restrict__ p, int n) {
  int i = blockIdx.x * 256 + threadIdx.x;
  if (i < n) p[i] = 0.f;
}

// ------- pass 1: x fp32 -> x_bf16, per-segment column sums -------
// block = 256 thr: 4 row-groups x 64 lanes (4 cols each). 128 rows/block.
__global__ __launch_bounds__(256) void k_segsum_convert(
    const float* __restrict__ x, const int* __restrict__ o,
    unsigned short* __restrict__ x_bf, float* __restrict__ seg_sums) {
  __shared__ int o_s[NSEG];
  int t = threadIdx.x;
  if (t < NSEG) o_s[t] = o[t];
  __syncthreads();
  int g = t >> 6, l = t & 63;
  int row0 = blockIdx.x * 128;
  int c0 = l * 4;
  int cur = 0;
  {
    int rf = row0 + g;
    while (o_s[cur] <= rf) ++cur;
  }
  float4 acc = {0.f, 0.f, 0.f, 0.f};
  const float4* xv = (const float4*)x;
  for (int i = 0; i < 32; ++i) {
    int r = row0 + g + i * 4;
    if (r >= o_s[cur]) {
      atomicAdd(&seg_sums[cur * NC + c0 + 0], acc.x);
      atomicAdd(&seg_sums[cur * NC + c0 + 1], acc.y);
      atomicAdd(&seg_sums[cur * NC + c0 + 2], acc.z);
      atomicAdd(&seg_sums[cur * NC + c0 + 3], acc.w);
      acc.x = acc.y = acc.z = acc.w = 0.f;
      do { ++cur; } while (o_s[cur] <= r);
    }
    float4 v = xv[r * 64 + l];
    ushort4 b;
    b.x = f2bf(v.x); b.y = f2bf(v.y); b.z = f2bf(v.z); b.w = f2bf(v.w);
    *(ushort4*)(x_bf + r * NC + c0) = b;
    acc.x += v.x; acc.y += v.y; acc.z += v.z; acc.w += v.w;
  }
  atomicAdd(&seg_sums[cur * NC + c0 + 0], acc.x);
  atomicAdd(&seg_sums[cur * NC + c0 + 1], acc.y);
  atomicAdd(&seg_sums[cur * NC + c0 + 2], acc.z);
  atomicAdd(&seg_sums[cur * NC + c0 + 3], acc.w);
}

// ------- transpose+convert W1_top (rows 0..255) -> bf16 [n][k] -------
__global__ void k_w1t(const float* __restrict__ W1, unsigned short* __restrict__ w1t) {
  int j = blockIdx.x, k = threadIdx.x;
  w1t[j * NC + k] = f2bf(W1[k * NC + j]);
}

// ------- tiny per-segment MLP: means -> y=relu(means@W2+b2) -> z=y@W1_bot+b1 -------
__global__ __launch_bounds__(256) void k_seg_mlp(
    const int* __restrict__ o, const float* __restrict__ seg_sums,
    const float* __restrict__ W1, const float* __restrict__ b1,
    const float* __restrict__ W2, const float* __restrict__ b2,
    float* __restrict__ z) {
  __shared__ float mean_s[NC];
  __shared__ float y_s[NC];
  int b = blockIdx.x, j = threadIdx.x;
  int start = (b == 0) ? 0 : o[b - 1];
  float inv = 1.f / (float)(o[b] - start);
  mean_s[j] = seg_sums[b * NC + j] * inv;
  __syncthreads();
  float a = b2[j];
  for (int k = 0; k < NC; ++k) a += mean_s[k] * W2[k * NC + j];
  y_s[j] = fmaxf(a, 0.f);
  __syncthreads();
  float a2 = b1[j];
  for (int k = 0; k < NC; ++k) a2 += y_s[k] * W1[(NC + k) * NC + j];
  z[b * NC + j] = a2;
}

// ------- main GEMM: h = x_bf @ W1_top + z[seg]; emit h_bf + BN col stats -------
// grid: 1024 row-tiles x 2 col-tiles; 128x128 tile, BK=32, 4 waves (2x2 of 64x64)
__global__ __launch_bounds__(256) void k_gemm(
    const unsigned short* __restrict__ x_bf, const unsigned short* __restrict__ w1t,
    const int* __restrict__ o, const float* __restrict__ z,
    unsigned short* __restrict__ h_bf,
    float* __restrict__ colsum, float* __restrict__ colsumsq) {
  __shared__ __align__(16) unsigned short lA[128 * 32];
  __shared__ __align__(16) unsigned short lB[128 * 32];
  __shared__ float s_sum[128];
  __shared__ float s_sq[128];
  __shared__ int o_s[NSEG];

  int t = threadIdx.x;
  int lane = t & 63, w = t >> 6;
  int wr = w >> 1, wc = w & 1;
  int bid = blockIdx.x;
  int ct = bid & 1, rt = bid >> 1;
  const int row0 = rt * 128, colT = ct * 128;

  if (t < 128) { s_sum[t] = 0.f; s_sq[t] = 0.f; }
  if (t < NSEG) o_s[t] = o[t];

  f32x4 acc[4][4] = {};

  for (int kt = 0; kt < 8; ++kt) {
    {
      int c = t;
      const unsigned short* ga = x_bf + (size_t)(row0 + (c >> 2)) * NC + kt * 32 + (c & 3) * 8;
      __builtin_amdgcn_global_load_lds(
          (const __attribute__((address_space(1))) void*)ga,
          (__attribute__((address_space(3))) void*)(lA + c * 8), 16, 0, 0);
      const unsigned short* gb = w1t + (size_t)(colT + (c >> 2)) * NC + kt * 32 + (c & 3) * 8;
      __builtin_amdgcn_global_load_lds(
          (const __attribute__((address_space(1))) void*)gb,
          (__attribute__((address_space(3))) void*)(lB + c * 8), 16, 0, 0);
      c = t + 256;
      ga = x_bf + (size_t)(row0 + (c >> 2)) * NC + kt * 32 + (c & 3) * 8;
      __builtin_amdgcn_global_load_lds(
          (const __attribute__((address_space(1))) void*)ga,
          (__attribute__((address_space(3))) void*)(lA + c * 8), 16, 0, 0);
      gb = w1t + (size_t)(colT + (c >> 2)) * NC + kt * 32 + (c & 3) * 8;
      __builtin_amdgcn_global_load_lds(
          (const __attribute__((address_space(1))) void*)gb,
          (__attribute__((address_space(3))) void*)(lB + c * 8), 16, 0, 0);
    }
    __syncthreads();
    bf16x8 af[4], bf[4];
#pragma unroll
    for (int m = 0; m < 4; ++m)
      af[m] = *(const bf16x8*)(lA + (wr * 64 + m * 16 + (lane & 15)) * 32 + (lane >> 4) * 8);
#pragma unroll
    for (int n = 0; n < 4; ++n)
      bf[n] = *(const bf16x8*)(lB + (wc * 64 + n * 16 + (lane & 15)) * 32 + (lane >> 4) * 8);
#pragma unroll
    for (int m = 0; m < 4; ++m)
#pragma unroll
      for (int n = 0; n < 4; ++n)
        acc[m][n] = __builtin_amdgcn_mfma_f32_16x16x32_bf16(af[m], bf[n], acc[m][n], 0, 0, 0);
    __syncthreads();
  }

  // epilogue: + z[seg], store h_bf, per-column sum/sumsq
  int s0 = 0;
  while (o_s[s0] <= row0) ++s0;
  int e0 = o_s[s0];
  int s1 = (s0 < NSEG - 1) ? s0 + 1 : s0;
  int cl = lane & 15, q = lane >> 4;
#pragma unroll
  for (int n = 0; n < 4; ++n) {
    int col = colT + wc * 64 + n * 16 + cl;
    float zA = z[s0 * NC + col], zB = z[s1 * NC + col];
    float ps = 0.f, pq = 0.f;
#pragma unroll
    for (int m = 0; m < 4; ++m) {
      int rbase = row0 + wr * 64 + m * 16 + q * 4;
#pragma unroll
      for (int r = 0; r < 4; ++r) {
        int row = rbase + r;
        float hv = acc[m][n][r] + ((row < e0) ? zA : zB);
        h_bf[(size_t)row * NC + col] = f2bf(hv);
        ps += hv; pq += hv * hv;
      }
    }
    ps += __shfl_xor(ps, 16, 64); ps += __shfl_xor(ps, 32, 64);
    pq += __shfl_xor(pq, 16, 64); pq += __shfl_xor(pq, 32, 64);
    if (q == 0) {
      atomicAdd(&s_sum[wc * 64 + n * 16 + cl], ps);
      atomicAdd(&s_sq[wc * 64 + n * 16 + cl], pq);
    }
  }
  __syncthreads();
  if (t < 128) {
    atomicAdd(&colsum[colT + t], s_sum[t]);
    atomicAdd(&colsumsq[colT + t], s_sq[t]);
  }
}

// ------- BN finalize: scale/shift per column -------
__global__ void k_bn_final(const float* __restrict__ colsum, const float* __restrict__ colsumsq,
                           const float* __restrict__ gamma, const float* __restrict__ beta,
                           float* __restrict__ scale, float* __restrict__ shift) {
  int t = threadIdx.x;
  float invN = 1.f / (float)N_PTS;
  float mu = colsum[t] * invN;
  float var = colsumsq[t] * invN - mu * mu;
  float sc = gamma[t] * rsqrtf(var + BN_EPSF);
  scale[t] = sc;
  shift[t] = beta[t] - mu * sc;
}

// ------- BN apply + ReLU: out = relu(h*scale + shift) -------
__global__ __launch_bounds__(256) void k_bn_apply(
    const unsigned short* __restrict__ h_bf, const float* __restrict__ scale,
    const float* __restrict__ shift, float* __restrict__ out) {
  __shared__ float s_sc[NC];
  __shared__ float s_sh[NC];
  int t = threadIdx.x;
  s_sc[t] = scale[t];
  s_sh[t] = shift[t];
  __syncthreads();
  size_t idx = (size_t)blockIdx.x * 256 + t;
  size_t l0 = idx * 8;
  int col = (int)(l0 & 255);
  uint4 hv = *(const uint4*)(h_bf + l0);
  float f0 = bf2f((unsigned short)(hv.x & 0xffffu));
  float f1 = bf2f((unsigned short)(hv.x >> 16));
  float f2 = bf2f((unsigned short)(hv.y & 0xffffu));
  float f3 = bf2f((unsigned short)(hv.y >> 16));
  float f4 = bf2f((unsigned short)(hv.z & 0xffffu));
  float f5 = bf2f((unsigned short)(hv.z >> 16));
  float f6 = bf2f((unsigned short)(hv.w & 0xffffu));
  float f7 = bf2f((unsigned short)(hv.w >> 16));
  float4 o0, o1;
  o0.x = fmaxf(f0 * s_sc[col + 0] + s_sh[col + 0], 0.f);
  o0.y = fmaxf(f1 * s_sc[col + 1] + s_sh[col + 1], 0.f);
  o0.z = fmaxf(f2 * s_sc[col + 2] + s_sh[col + 2], 0.f);
  o0.w = fmaxf(f3 * s_sc[col + 3] + s_sh[col + 3], 0.f);
  o1.x = fmaxf(f4 * s_sc[col + 4] + s_sh[col + 4], 0.f);
  o1.y = fmaxf(f5 * s_sc[col + 5] + s_sh[col + 5], 0.f);
  o1.z = fmaxf(f6 * s_sc[col + 6] + s_sh[col + 6], 0.f);
  o1.w = fmaxf(f7 * s_sc[col + 7] + s_sh[col + 7], 0.f);
  *(float4*)(out + l0) = o0;
  *(float4*)(out + l0 + 4) = o1;
}

extern "C" void kernel_launch(void* const* d_in, const int* in_sizes, int n_in,
                              void* d_out, int out_size, void* d_ws, size_t ws_size,
                              hipStream_t stream) {
  const float* x = (const float*)d_in[0];
  const int* o = (const int*)d_in[1];
  const float* W1 = (const float*)d_in[2];
  const float* b1 = (const float*)d_in[3];
  const float* W2 = (const float*)d_in[4];
  const float* b2 = (const float*)d_in[5];
  const float* gamma = (const float*)d_in[6];
  const float* beta = (const float*)d_in[7];
  float* out = (float*)d_out;

  char* ws = (char*)d_ws;
  unsigned short* x_bf = (unsigned short*)ws;                  // 64 MiB
  unsigned short* h_bf = (unsigned short*)(ws + 67108864);     // 64 MiB
  char* base2 = ws + 134217728;
  float* seg_sums = (float*)(base2);            // 16 KiB   (zeroed)
  float* colsum   = (float*)(base2 + 16384);    // 1 KiB    (zeroed)
  float* colsumsq = (float*)(base2 + 17408);    // 1 KiB    (zeroed)
  float* z        = (float*)(base2 + 18432);    // 16 KiB
  float* scale    = (float*)(base2 + 34816);    // 1 KiB
  float* shift    = (float*)(base2 + 35840);    // 1 KiB
  unsigned short* w1t = (unsigned short*)(base2 + 36864);      // 128 KiB

  k_zero<<<18, 256, 0, stream>>>(seg_sums, 4608);  // seg_sums+colsum+colsumsq contiguous
  k_segsum_convert<<<1024, 256, 0, stream>>>(x, o, x_bf, seg_sums);
  k_w1t<<<256, 256, 0, stream>>>(W1, w1t);
  k_seg_mlp<<<16, 256, 0, stream>>>(o, seg_sums, W1, b1, W2, b2, z);
  k_gemm<<<2048, 256, 0, stream>>>(x_bf, w1t, o, z, h_bf, colsum, colsumsq);
  k_bn_final<<<1, 256, 0, stream>>>(colsum, colsumsq, gamma, beta, scale, shift);
  k_bn_apply<<<16384, 256, 0, stream>>>(h_bf, scale, shift, out);
}

// Round 2
// 349.972 us; speedup vs baseline: 1.0870x; 1.0870x over previous
//
#include <hip/hip_runtime.h>
#include <hip/hip_bf16.h>
#include <stdint.h>

#define N_PTS 131072
#define NC 256
#define NSEG 16
#define BN_EPSF 1e-5f

typedef __attribute__((ext_vector_type(8))) short bf16x8;
typedef __attribute__((ext_vector_type(4))) float f32x4;

__device__ __forceinline__ unsigned short f2bf(float f) {
  union { float f; uint32_t u; } v; v.f = f;
  uint32_t u = v.u;
  uint32_t r = (u + 0x7fffu + ((u >> 16) & 1u)) >> 16;
  return (unsigned short)r;
}
__device__ __forceinline__ float bf2f(unsigned short h) {
  union { uint32_t u; float f; } v; v.u = ((uint32_t)h) << 16; return v.f;
}

// ---------------- zero scratch stats ----------------
__global__ void k_zero(float* __restrict__ p, int n) {
  int i = blockIdx.x * 256 + threadIdx.x;
  if (i < n) p[i] = 0.f;
}

// ------- pass 1: x fp32 -> x_bf16, per-segment column sums -------
// 2048 blocks x 64 rows. Branchless (<=2 segments per 64-row block),
// fully unrolled so the 16 float4 loads pipeline.
__global__ __launch_bounds__(256) void k_segsum_convert(
    const float* __restrict__ x, const int* __restrict__ o,
    unsigned short* __restrict__ x_bf, float* __restrict__ seg_sums) {
  __shared__ int o_s[NSEG];
  __shared__ float s_acc[2][NC];
  int t = threadIdx.x;
  if (t < NSEG) o_s[t] = o[t];
  s_acc[0][t] = 0.f;
  s_acc[1][t] = 0.f;
  __syncthreads();
  int g = t >> 6, l = t & 63;
  int row0 = blockIdx.x * 64;
  int c0 = l * 4;
  int s0 = 0;
  while (o_s[s0] <= row0) ++s0;
  int e0 = o_s[s0];
  int s1 = (s0 < NSEG - 1) ? s0 + 1 : s0;  // if s1==s0, accB stays 0 -> harmless
  float4 accA = {0.f, 0.f, 0.f, 0.f}, accB = {0.f, 0.f, 0.f, 0.f};
  const float4* xv = (const float4*)x;
#pragma unroll
  for (int i = 0; i < 16; ++i) {
    int r = row0 + g + i * 4;
    float4 v = xv[(size_t)r * 64 + l];
    ushort4 b;
    b.x = f2bf(v.x); b.y = f2bf(v.y); b.z = f2bf(v.z); b.w = f2bf(v.w);
    *(ushort4*)(x_bf + (size_t)r * NC + c0) = b;
    bool inA = (r < e0);
    accA.x += inA ? v.x : 0.f; accB.x += inA ? 0.f : v.x;
    accA.y += inA ? v.y : 0.f; accB.y += inA ? 0.f : v.y;
    accA.z += inA ? v.z : 0.f; accB.z += inA ? 0.f : v.z;
    accA.w += inA ? v.w : 0.f; accB.w += inA ? 0.f : v.w;
  }
  atomicAdd(&s_acc[0][c0 + 0], accA.x);
  atomicAdd(&s_acc[0][c0 + 1], accA.y);
  atomicAdd(&s_acc[0][c0 + 2], accA.z);
  atomicAdd(&s_acc[0][c0 + 3], accA.w);
  atomicAdd(&s_acc[1][c0 + 0], accB.x);
  atomicAdd(&s_acc[1][c0 + 1], accB.y);
  atomicAdd(&s_acc[1][c0 + 2], accB.z);
  atomicAdd(&s_acc[1][c0 + 3], accB.w);
  __syncthreads();
  atomicAdd(&seg_sums[s0 * NC + t], s_acc[0][t]);
  atomicAdd(&seg_sums[s1 * NC + t], s_acc[1][t]);
}

// ------- transpose+convert W1_top (rows 0..255) -> bf16 [n][k], LDS-tiled -------
__global__ __launch_bounds__(256) void k_w1t(const float* __restrict__ W1,
                                             unsigned short* __restrict__ w1t) {
  __shared__ float tile[64][65];
  int t = threadIdx.x;
  int bx = blockIdx.x & 3, by = blockIdx.x >> 2;
  int k0 = by * 64, j0 = bx * 64;
  int r = t >> 6, c = t & 63;
#pragma unroll
  for (int i = 0; i < 16; ++i) {
    int kk = r + i * 4;
    tile[kk][c] = W1[(size_t)(k0 + kk) * NC + j0 + c];
  }
  __syncthreads();
#pragma unroll
  for (int i = 0; i < 16; ++i) {
    int jj = r + i * 4;
    w1t[(size_t)(j0 + jj) * NC + k0 + c] = f2bf(tile[c][jj]);
  }
}

// ------- tiny per-segment MLP: means -> y=relu(means@W2+b2) -> z=y@W1_bot+b1 -------
__global__ __launch_bounds__(256) void k_seg_mlp(
    const int* __restrict__ o, const float* __restrict__ seg_sums,
    const float* __restrict__ W1, const float* __restrict__ b1,
    const float* __restrict__ W2, const float* __restrict__ b2,
    float* __restrict__ z) {
  __shared__ float mean_s[NC];
  __shared__ float y_s[NC];
  int b = blockIdx.x, j = threadIdx.x;
  int start = (b == 0) ? 0 : o[b - 1];
  float inv = 1.f / (float)(o[b] - start);
  mean_s[j] = seg_sums[b * NC + j] * inv;
  __syncthreads();
  float a = b2[j];
  for (int k = 0; k < NC; ++k) a += mean_s[k] * W2[k * NC + j];
  y_s[j] = fmaxf(a, 0.f);
  __syncthreads();
  float a2 = b1[j];
  for (int k = 0; k < NC; ++k) a2 += y_s[k] * W1[(NC + k) * NC + j];
  z[b * NC + j] = a2;
}

// ------- main GEMM: h = x_bf @ W1_top + z[seg]; emit h_bf + BN col stats -------
// grid: 1024 row-tiles x 2 col-tiles; 128x128 tile, BK=32, 4 waves (2x2 of 64x64)
__global__ __launch_bounds__(256) void k_gemm(
    const unsigned short* __restrict__ x_bf, const unsigned short* __restrict__ w1t,
    const int* __restrict__ o, const float* __restrict__ z,
    unsigned short* __restrict__ h_bf,
    float* __restrict__ colsum, float* __restrict__ colsumsq) {
  __shared__ __align__(16) unsigned short lA[128 * 32];
  __shared__ __align__(16) unsigned short lB[128 * 32];
  __shared__ float s_sum[128];
  __shared__ float s_sq[128];
  __shared__ int o_s[NSEG];

  int t = threadIdx.x;
  int lane = t & 63, w = t >> 6;
  int wr = w >> 1, wc = w & 1;
  int bid = blockIdx.x;
  int ct = bid & 1, rt = bid >> 1;
  const int row0 = rt * 128, colT = ct * 128;

  if (t < 128) { s_sum[t] = 0.f; s_sq[t] = 0.f; }
  if (t < NSEG) o_s[t] = o[t];

  f32x4 acc[4][4] = {};

  for (int kt = 0; kt < 8; ++kt) {
    {
      int c = t;
      const unsigned short* ga = x_bf + (size_t)(row0 + (c >> 2)) * NC + kt * 32 + (c & 3) * 8;
      __builtin_amdgcn_global_load_lds(
          (const __attribute__((address_space(1))) void*)ga,
          (__attribute__((address_space(3))) void*)(lA + c * 8), 16, 0, 0);
      const unsigned short* gb = w1t + (size_t)(colT + (c >> 2)) * NC + kt * 32 + (c & 3) * 8;
      __builtin_amdgcn_global_load_lds(
          (const __attribute__((address_space(1))) void*)gb,
          (__attribute__((address_space(3))) void*)(lB + c * 8), 16, 0, 0);
      c = t + 256;
      ga = x_bf + (size_t)(row0 + (c >> 2)) * NC + kt * 32 + (c & 3) * 8;
      __builtin_amdgcn_global_load_lds(
          (const __attribute__((address_space(1))) void*)ga,
          (__attribute__((address_space(3))) void*)(lA + c * 8), 16, 0, 0);
      gb = w1t + (size_t)(colT + (c >> 2)) * NC + kt * 32 + (c & 3) * 8;
      __builtin_amdgcn_global_load_lds(
          (const __attribute__((address_space(1))) void*)gb,
          (__attribute__((address_space(3))) void*)(lB + c * 8), 16, 0, 0);
    }
    __syncthreads();
    bf16x8 af[4], bf[4];
#pragma unroll
    for (int m = 0; m < 4; ++m)
      af[m] = *(const bf16x8*)(lA + (wr * 64 + m * 16 + (lane & 15)) * 32 + (lane >> 4) * 8);
#pragma unroll
    for (int n = 0; n < 4; ++n)
      bf[n] = *(const bf16x8*)(lB + (wc * 64 + n * 16 + (lane & 15)) * 32 + (lane >> 4) * 8);
#pragma unroll
    for (int m = 0; m < 4; ++m)
#pragma unroll
      for (int n = 0; n < 4; ++n)
        acc[m][n] = __builtin_amdgcn_mfma_f32_16x16x32_bf16(af[m], bf[n], acc[m][n], 0, 0, 0);
    __syncthreads();
  }

  // epilogue: + z[seg], store h_bf, per-column sum/sumsq
  int s0 = 0;
  while (o_s[s0] <= row0) ++s0;
  int e0 = o_s[s0];
  int s1 = (s0 < NSEG - 1) ? s0 + 1 : s0;
  int cl = lane & 15, q = lane >> 4;
#pragma unroll
  for (int n = 0; n < 4; ++n) {
    int col = colT + wc * 64 + n * 16 + cl;
    float zA = z[s0 * NC + col], zB = z[s1 * NC + col];
    float ps = 0.f, pq = 0.f;
#pragma unroll
    for (int m = 0; m < 4; ++m) {
      int rbase = row0 + wr * 64 + m * 16 + q * 4;
#pragma unroll
      for (int r = 0; r < 4; ++r) {
        int row = rbase + r;
        float hv = acc[m][n][r] + ((row < e0) ? zA : zB);
        h_bf[(size_t)row * NC + col] = f2bf(hv);
        ps += hv; pq += hv * hv;
      }
    }
    ps += __shfl_xor(ps, 16, 64); ps += __shfl_xor(ps, 32, 64);
    pq += __shfl_xor(pq, 16, 64); pq += __shfl_xor(pq, 32, 64);
    if (q == 0) {
      atomicAdd(&s_sum[wc * 64 + n * 16 + cl], ps);
      atomicAdd(&s_sq[wc * 64 + n * 16 + cl], pq);
    }
  }
  __syncthreads();
  if (t < 128) {
    atomicAdd(&colsum[colT + t], s_sum[t]);
    atomicAdd(&colsumsq[colT + t], s_sq[t]);
  }
}

// ------- BN finalize: scale/shift per column -------
__global__ void k_bn_final(const float* __restrict__ colsum, const float* __restrict__ colsumsq,
                           const float* __restrict__ gamma, const float* __restrict__ beta,
                           float* __restrict__ scale, float* __restrict__ shift) {
  int t = threadIdx.x;
  float invN = 1.f / (float)N_PTS;
  float mu = colsum[t] * invN;
  float var = colsumsq[t] * invN - mu * mu;
  float sc = gamma[t] * rsqrtf(var + BN_EPSF);
  scale[t] = sc;
  shift[t] = beta[t] - mu * sc;
}

// ------- BN apply + ReLU: out = relu(h*scale + shift), 4 elems/thread -------
__global__ __launch_bounds__(256) void k_bn_apply(
    const unsigned short* __restrict__ h_bf, const float* __restrict__ scale,
    const float* __restrict__ shift, float* __restrict__ out) {
  int t = threadIdx.x;
  size_t idx = (size_t)blockIdx.x * 256 + t;
  size_t l0 = idx * 4;
  int col = (int)(l0 & 255);
  uint2 hv = *(const uint2*)(h_bf + l0);
  float4 sc = *(const float4*)(scale + col);
  float4 sh = *(const float4*)(shift + col);
  float f0 = bf2f((unsigned short)(hv.x & 0xffffu));
  float f1 = bf2f((unsigned short)(hv.x >> 16));
  float f2 = bf2f((unsigned short)(hv.y & 0xffffu));
  float f3 = bf2f((unsigned short)(hv.y >> 16));
  float4 o0;
  o0.x = fmaxf(f0 * sc.x + sh.x, 0.f);
  o0.y = fmaxf(f1 * sc.y + sh.y, 0.f);
  o0.z = fmaxf(f2 * sc.z + sh.z, 0.f);
  o0.w = fmaxf(f3 * sc.w + sh.w, 0.f);
  *(float4*)(out + l0) = o0;
}

extern "C" void kernel_launch(void* const* d_in, const int* in_sizes, int n_in,
                              void* d_out, int out_size, void* d_ws, size_t ws_size,
                              hipStream_t stream) {
  const float* x = (const float*)d_in[0];
  const int* o = (const int*)d_in[1];
  const float* W1 = (const float*)d_in[2];
  const float* b1 = (const float*)d_in[3];
  const float* W2 = (const float*)d_in[4];
  const float* b2 = (const float*)d_in[5];
  const float* gamma = (const float*)d_in[6];
  const float* beta = (const float*)d_in[7];
  float* out = (float*)d_out;

  char* ws = (char*)d_ws;
  unsigned short* x_bf = (unsigned short*)ws;                  // 64 MiB
  unsigned short* h_bf = (unsigned short*)(ws + 67108864);     // 64 MiB
  char* base2 = ws + 134217728;
  float* seg_sums = (float*)(base2);            // 16 KiB   (zeroed)
  float* colsum   = (float*)(base2 + 16384);    // 1 KiB    (zeroed)
  float* colsumsq = (float*)(base2 + 17408);    // 1 KiB    (zeroed)
  float* z        = (float*)(base2 + 18432);    // 16 KiB
  float* scale    = (float*)(base2 + 34816);    // 1 KiB
  float* shift    = (float*)(base2 + 35840);    // 1 KiB
  unsigned short* w1t = (unsigned short*)(base2 + 36864);      // 128 KiB

  k_zero<<<18, 256, 0, stream>>>(seg_sums, 4608);  // seg_sums+colsum+colsumsq contiguous
  k_segsum_convert<<<2048, 256, 0, stream>>>(x, o, x_bf, seg_sums);
  k_w1t<<<16, 256, 0, stream>>>(W1, w1t);
  k_seg_mlp<<<16, 256, 0, stream>>>(o, seg_sums, W1, b1, W2, b2, z);
  k_gemm<<<2048, 256, 0, stream>>>(x_bf, w1t, o, z, h_bf, colsum, colsumsq);
  k_bn_final<<<1, 256, 0, stream>>>(colsum, colsumsq, gamma, beta, scale, shift);
  k_bn_apply<<<32768, 256, 0, stream>>>(h_bf, scale, shift, out);
}